// Round 19
// baseline (395.451 us; speedup 1.0000x reference)
//
#include <hip/hip_runtime.h>

#define NPTS 16384
#define DH 256
#define PH 4096
#define D2 512

typedef _Float16 f16;
typedef _Float16 f16x4 __attribute__((ext_vector_type(4)));
typedef _Float16 f16x8 __attribute__((ext_vector_type(8)));
typedef float f32x4 __attribute__((ext_vector_type(4)));

// Static device scratch; rewritten every call.
// FRAGMENT-ORDERED B layouts (R18): g_eAtF[dblk6][nblk][lane][8] such that a
// wave's MFMA B-frag (16 d-rows x 32 k) is 64 lanes x 16 B CONTIGUOUS ->
// one coalesced 1 KB global load per frag, B never touches LDS.
//   value (d, n): dblk6=d>>4, nblk=n>>5, lane=(d&15)|(((n>>3)&3)<<4), j=n&7.
__device__ f16   g_eAtF[32][512][64][8];   // 16 MB: eA^T fragment-ordered
__device__ f16   g_Tt[4][D2][2*PH];        // 64 MB: T K-split partials (linear)
__device__ f16   g_TsF[32][256][64][8];    //  8 MB: T summed, fragment-ordered (ik)
__device__ float g_G[2][NPTS][D2];         // 64 MB: G K-split partials

__device__ __forceinline__ void fsincos(float x, float* s, float* c) {
    *s = __sinf(x); *c = __cosf(x);
}

// ---------------------------------------------------------------------------
// eA^T precompute into fragment order. cos -> dblk6 = dd>>4, sin -> +16.
// ---------------------------------------------------------------------------
__global__ __launch_bounds__(256) void ker_pre(const float* __restrict__ pts,
                                               const float* __restrict__ A) {
    const int dd = blockIdx.x;           // 0..255
    const int t  = threadIdx.x;          // 64-col chunk c = t
    const float a0 = A[dd], a1 = A[DH + dd], a2 = A[2*DH + dd];
    const int dblkC = dd >> 4;
    const int dblkS = (dd >> 4) + 16;
    const int lanelo = dd & 15;
    #pragma unroll
    for (int s = 0; s < 8; ++s) {
        const int n0 = t*64 + 8*s;
        f16x8 vc, vs;
        #pragma unroll
        for (int i = 0; i < 8; ++i) {
            const float* pr = pts + (size_t)(n0 + i)*3;
            float sn, cs_; fsincos(pr[0]*a0 + pr[1]*a1 + pr[2]*a2, &sn, &cs_);
            vc[i] = (f16)cs_; vs[i] = (f16)sn;
        }
        const int nblk = n0 >> 5;                    // t*2 + (s>>2)
        const int lane = lanelo | ((s & 3) << 4);    // (n0>>3)&3 == s&3
        *(f16x8*)&g_eAtF[dblkC][nblk][lane][0] = vc;
        *(f16x8*)&g_eAtF[dblkS][nblk][lane][0] = vs;
    }
}

// ---------------------------------------------------------------------------
// GEMM1: T = eB^T eA. Block: M=128 (64 q x {cos,sin}), N=256 d, BK=64 n.
// Grid (64,2,4) = 1024 blocks. 512 thr, 8 waves (2M x 4N), wave-tile 64x64.
// R18: B-frags loaded DIRECTLY from fragment-ordered global (coalesced 1KB
// per frag, L2/L3-resident) -- B out of LDS entirely (-53% LDS traffic).
// A (eB) trig -> XOR-swizzled ds_write [128][64] (R12 verbatim, 0 conflicts).
// ---------------------------------------------------------------------------
__global__ __launch_bounds__(512) void ker_T(const float* __restrict__ pts,
                                             const float* __restrict__ B) {
    const int q0 = blockIdx.x * 64;
    const int d0 = blockIdx.y * 256;
    const int ks = blockIdx.z;               // n range [ks*4096, +4096)
    const int t  = threadIdx.x;
    const int lane = t & 63, wid = t >> 6;
    const int wm = wid >> 2, wn = wid & 3;
    const int l7 = lane & 7;

    __shared__ f16 Al[128][64];    // rows 0..63 cos q, 64..127 sin q (XOR-swz)

    f32x4 acc[4][4];
    #pragma unroll
    for (int a = 0; a < 4; ++a)
        #pragma unroll
        for (int bq = 0; bq < 4; ++bq) acc[a][bq] = (f32x4){0.f,0.f,0.f,0.f};

    // A-trig: qq = t>>3 (0..63), 8 n per iter, logical slot t&7
    const int qq  = t >> 3;
    const int nn0 = (t & 7) * 8;
    const int wsl = ((t & 7) ^ (qq & 7)) * 8;
    const float b0 = B[q0+qq], b1 = B[PH+q0+qq], b2 = B[2*PH+q0+qq];
    const int mrow = wm*64 + (lane & 15);
    // B fragment pointers: one per nf (dblk6 = (d0>>4)+wn*4+nf), nblk = ks*128+c*2+kk
    const f16* pF[4];
    #pragma unroll
    for (int nf = 0; nf < 4; ++nf)
        pF[nf] = &g_eAtF[(d0 >> 4) + wn*4 + nf][ks*128][lane][0];

    for (int c = 0; c < 64; ++c) {
        const int nb = ks*4096 + c*64;
        __syncthreads();   // previous compute's LDS reads done
        {   // A stage: 8 consecutive pts rows = 24 contiguous floats (R12)
            const float* pb = pts + (size_t)(nb + nn0)*3;
            const float4 F0 = *(const float4*)(pb);
            const float4 F1 = *(const float4*)(pb + 4);
            const float4 F2 = *(const float4*)(pb + 8);
            const float4 F3 = *(const float4*)(pb + 12);
            const float4 F4 = *(const float4*)(pb + 16);
            const float4 F5 = *(const float4*)(pb + 20);
            const float xx[8] = {F0.x, F0.w, F1.z, F2.y, F3.x, F3.w, F4.z, F5.y};
            const float yy[8] = {F0.y, F1.x, F1.w, F2.z, F3.y, F4.x, F4.w, F5.z};
            const float zz[8] = {F0.z, F1.y, F2.x, F2.w, F3.z, F4.y, F5.x, F5.w};
            f16x8 vc, vs;
            #pragma unroll
            for (int u = 0; u < 8; ++u) {
                float sn, cc; fsincos(xx[u]*b0 + yy[u]*b1 + zz[u]*b2, &sn, &cc);
                vc[u] = (f16)cc; vs[u] = (f16)sn;
            }
            *(f16x8*)&Al[qq][wsl]      = vc;   // (64+qq)&7 == qq&7
            *(f16x8*)&Al[64 + qq][wsl] = vs;
        }
        __syncthreads();
        // compute: B-frags (coalesced global, issued first) + A-frags + MFMA
        f16x8 bf[2][4], af[2][4];
        #pragma unroll
        for (int kk = 0; kk < 2; ++kk)
            #pragma unroll
            for (int nf = 0; nf < 4; ++nf)
                bf[kk][nf] = *(const f16x8*)(pF[nf] + (size_t)(c*2 + kk)*64*8);
        #pragma unroll
        for (int kk = 0; kk < 2; ++kk)
            #pragma unroll
            for (int mf = 0; mf < 4; ++mf)   // (mrow+mf*16)&7 == l7
                af[kk][mf] = *(const f16x8*)&Al[mrow + mf*16][(((lane >> 4) + 4*kk) ^ l7)*8];
        #pragma unroll
        for (int kk = 0; kk < 2; ++kk)
            #pragma unroll
            for (int mf = 0; mf < 4; ++mf)
                #pragma unroll
                for (int nf = 0; nf < 4; ++nf)
                    acc[mf][nf] = __builtin_amdgcn_mfma_f32_16x16x32_f16(
                        af[kk][mf], bf[kk][nf], acc[mf][nf], 0, 0, 0);
    }

    // epilogue: wave wm: 0=cos rows, 1=sin rows; D row=(l>>4)*4+j, col=l&15
    #pragma unroll
    for (int mf = 0; mf < 4; ++mf) {
        const int qrow = q0 + mf*16 + (lane >> 4)*4;
        #pragma unroll
        for (int nf = 0; nf < 4; ++nf) {
            const int d = d0 + wn*64 + nf*16 + (lane & 15);
            f16x4 v;
            #pragma unroll
            for (int j = 0; j < 4; ++j) v[j] = (f16)acc[mf][nf][j];
            *(f16x4*)&g_Tt[ks][d][(size_t)wm*PH + qrow] = v;
        }
    }
}

// ---------------------------------------------------------------------------
// Sum 4 T partials -> g_TsF fragment-ordered, interleaved ik = 2q+cs:
// (d, ik): dblk6=d>>4, ikblk=ik>>5, lane=(d&15)|(((ik>>3)&3)<<4), j=ik&7.
// Thread handles ik chunk jj*8 (jj = 0..1023): ikblk=jj>>2, lane-hi=jj&3.
// ---------------------------------------------------------------------------
__global__ __launch_bounds__(256) void ker_tsum() {
    const int u  = blockIdx.x*256 + threadIdx.x;   // 2048 blocks x 256 thr
    const int d  = u >> 10;                        // 0..511
    const int jj = u & 1023;
    const int q0_ = jj * 4;
    float oc[4] = {0,0,0,0}, os[4] = {0,0,0,0};
    #pragma unroll
    for (int z = 0; z < 4; ++z) {
        const f16x4 a  = *(const f16x4*)&g_Tt[z][d][q0_];
        const f16x4 bs = *(const f16x4*)&g_Tt[z][d][PH + q0_];
        #pragma unroll
        for (int j = 0; j < 4; ++j) { oc[j] += (float)a[j]; os[j] += (float)bs[j]; }
    }
    f16x8 v;
    #pragma unroll
    for (int j = 0; j < 4; ++j) { v[2*j] = (f16)oc[j]; v[2*j+1] = (f16)os[j]; }
    const int lane = (d & 15) | ((jj & 3) << 4);
    *(f16x8*)&g_TsF[d >> 4][jj >> 2][lane][0] = v;
}

// ---------------------------------------------------------------------------
// GEMM2: G = eB T. Block: M=128 n, N=256 d, BK=64 interleaved k (=32 q x cs).
// Grid (128,2,2) = 512 blocks. Same R18 direct-fragment-B schedule.
// A (eB cos/sin interleaved) trig -> XOR-swizzled ds_write [128][64] (R12).
// ---------------------------------------------------------------------------
__global__ __launch_bounds__(512) void ker_G(const float* __restrict__ pts,
                                             const float* __restrict__ B) {
    const int n0 = blockIdx.x * 128;
    const int d0 = blockIdx.y * 256;
    const int ks = blockIdx.z;               // ik range [ks*4096, +4096)
    const int t  = threadIdx.x;
    const int lane = t & 63, wid = t >> 6;
    const int wm = wid >> 2, wn = wid & 3;
    const int l7 = lane & 7;

    __shared__ f16 Al[128][64];    // [n][ik] XOR-swizzled

    f32x4 acc[4][4];
    #pragma unroll
    for (int a = 0; a < 4; ++a)
        #pragma unroll
        for (int bq = 0; bq < 4; ++bq) acc[a][bq] = (f32x4){0.f,0.f,0.f,0.f};

    // A-trig: nn = t>>2 (0..127); logical slots 2*(t&3), 2*(t&3)+1 (R12)
    const int nn   = t >> 2;
    const int qch8 = (t & 3) * 8;
    const int sl0  = 2*(t & 3);
    const int sx   = nn & 7;
    const float px = pts[(size_t)(n0+nn)*3];
    const float py = pts[(size_t)(n0+nn)*3 + 1];
    const float pz = pts[(size_t)(n0+nn)*3 + 2];
    const int mrow = wm*64 + (lane & 15);
    // B fragment pointers (g_TsF): dblk6 = (d0>>4)+wn*4+nf, ikblk = ks*128+c*2+kk
    const f16* pF[4];
    #pragma unroll
    for (int nf = 0; nf < 4; ++nf)
        pF[nf] = &g_TsF[(d0 >> 4) + wn*4 + nf][ks*128][lane][0];

    for (int c = 0; c < 64; ++c) {
        const int ikb = ks*4096 + c*64;
        const int qb  = ikb >> 1;
        __syncthreads();
        {   // A stage: 8 betas -> 16 interleaved (cos,sin) halfs (R12)
            const int qg = qb + qch8;
            const float4 X0 = *(const float4*)&B[qg];
            const float4 X1 = *(const float4*)&B[qg + 4];
            const float4 Y0 = *(const float4*)&B[PH + qg];
            const float4 Y1 = *(const float4*)&B[PH + qg + 4];
            const float4 Z0 = *(const float4*)&B[2*PH + qg];
            const float4 Z1 = *(const float4*)&B[2*PH + qg + 4];
            const float bx[8] = {X0.x,X0.y,X0.z,X0.w, X1.x,X1.y,X1.z,X1.w};
            const float by[8] = {Y0.x,Y0.y,Y0.z,Y0.w, Y1.x,Y1.y,Y1.z,Y1.w};
            const float bz[8] = {Z0.x,Z0.y,Z0.z,Z0.w, Z1.x,Z1.y,Z1.z,Z1.w};
            f16x8 v0, v1;
            #pragma unroll
            for (int u = 0; u < 8; ++u) {
                float sn, cc; fsincos(px*bx[u] + py*by[u] + pz*bz[u], &sn, &cc);
                if (u < 4) { v0[2*u]     = (f16)cc; v0[2*u+1]     = (f16)sn; }
                else       { v1[2*(u-4)] = (f16)cc; v1[2*(u-4)+1] = (f16)sn; }
            }
            *(f16x8*)&Al[nn][((sl0    ) ^ sx)*8] = v0;
            *(f16x8*)&Al[nn][((sl0 + 1) ^ sx)*8] = v1;
        }
        __syncthreads();
        f16x8 bf[2][4], af[2][4];
        #pragma unroll
        for (int kk = 0; kk < 2; ++kk)
            #pragma unroll
            for (int nf = 0; nf < 4; ++nf)
                bf[kk][nf] = *(const f16x8*)(pF[nf] + (size_t)(c*2 + kk)*64*8);
        #pragma unroll
        for (int kk = 0; kk < 2; ++kk)
            #pragma unroll
            for (int mf = 0; mf < 4; ++mf)   // (mrow+mf*16)&7 == l7
                af[kk][mf] = *(const f16x8*)&Al[mrow + mf*16][(((lane >> 4) + 4*kk) ^ l7)*8];
        #pragma unroll
        for (int kk = 0; kk < 2; ++kk)
            #pragma unroll
            for (int mf = 0; mf < 4; ++mf)
                #pragma unroll
                for (int nf = 0; nf < 4; ++nf)
                    acc[mf][nf] = __builtin_amdgcn_mfma_f32_16x16x32_f16(
                        af[kk][mf], bf[kk][nf], acc[mf][nf], 0, 0, 0);
    }

    // epilogue -> g_G[ks][n][d] fp32
    #pragma unroll
    for (int mf = 0; mf < 4; ++mf) {
        const int nbase = n0 + wm*64 + mf*16 + (lane >> 4)*4;
        #pragma unroll
        for (int nf = 0; nf < 4; ++nf) {
            const int d = d0 + wn*64 + nf*16 + (lane & 15);
            #pragma unroll
            for (int j = 0; j < 4; ++j)
                g_G[ks][nbase + j][d] = acc[mf][nf][j];
        }
    }
}

// ---------------------------------------------------------------------------
// Epilogue: Gc = (Gr+i*Gi)*conj(e^{i alpha}) (|e^{ia}|=1, divide==conj-mult;
// rotation preserves row norm -> scale = 16/||G row||). Output = REAL part.
// ---------------------------------------------------------------------------
__global__ __launch_bounds__(256) void ker_fin(const float* __restrict__ pts,
                                               const float* __restrict__ A,
                                               float* __restrict__ out) {
    const int n = blockIdx.x;
    const int k = threadIdx.x;  // 0..255
    const float p0 = pts[(size_t)n*3], p1 = pts[(size_t)n*3+1], p2 = pts[(size_t)n*3+2];
    const float alp = p0*A[k] + p1*A[DH + k] + p2*A[2*DH + k];
    float sa, ca; fsincos(alp, &sa, &ca);
    const float Gr = g_G[0][n][k]      + g_G[1][n][k];
    const float Gi = g_G[0][n][DH + k] + g_G[1][n][DH + k];
    const float Re = Gr*ca + Gi*sa;
    float nr = Gr*Gr + Gi*Gi;
    #pragma unroll
    for (int off = 32; off > 0; off >>= 1) nr += __shfl_down(nr, off, 64);
    __shared__ float wsum[4];
    if ((k & 63) == 0) wsum[k >> 6] = nr;
    __syncthreads();
    const float total = wsum[0] + wsum[1] + wsum[2] + wsum[3];
    const float scale = 16.0f * rsqrtf(total);
    out[(size_t)n*DH + k] = Re * scale;
}

extern "C" void kernel_launch(void* const* d_in, const int* in_sizes, int n_in,
                              void* d_out, int out_size, void* d_ws, size_t ws_size,
                              hipStream_t stream) {
    const float* pts = (const float*)d_in[0];
    const float* A   = (const float*)d_in[1];
    const float* B   = (const float*)d_in[2];
    float* out = (float*)d_out;
    (void)d_ws; (void)ws_size; (void)out_size;

    ker_pre <<<256, 256, 0, stream>>>(pts, A);
    ker_T   <<<dim3(64, 2, 4), 512, 0, stream>>>(pts, B);
    ker_tsum<<<2048, 256, 0, stream>>>();
    ker_G   <<<dim3(128, 2, 2), 512, 0, stream>>>(pts, B);
    ker_fin <<<16384, 256, 0, stream>>>(pts, A, out);
}

// Round 20
// 353.860 us; speedup vs baseline: 1.1175x; 1.1175x over previous
//
#include <hip/hip_runtime.h>

#define NPTS 16384
#define DH 256
#define PH 4096
#define D2 512

typedef _Float16 f16;
typedef _Float16 f16x4 __attribute__((ext_vector_type(4)));
typedef _Float16 f16x8 __attribute__((ext_vector_type(8)));
typedef float f32x4 __attribute__((ext_vector_type(4)));

// Static device scratch. Swizzle convention (all LDS tiles + pre-swizzled
// globals): within each 64-half (128 B) row chunk, physical 16B slot s holds
// logical slot s^(row&7)  (R7/R12: SQ_LDS_BANK_CONFLICT == 0).
__device__ f16   g_eAtS[(size_t)D2 * NPTS];   // 16 MB: eA^T fp16, swizzled
__device__ f16   g_Tt[4][D2][2*PH];           // 64 MB: T K-split partials [z][d][cs*PH+q]
__device__ f16   g_TsS[(size_t)D2 * 2*PH];    //  8 MB: T summed, [d][2q+cs] swizzled
__device__ float g_G[2][NPTS][D2];            // 64 MB: G K-split partials

__device__ __forceinline__ void gload16(const void* g, void* l) {
    __builtin_amdgcn_global_load_lds((const __attribute__((address_space(1))) void*)g,
                                     (__attribute__((address_space(3))) void*)l, 16, 0, 0);
}

__device__ __forceinline__ void fsincos(float x, float* s, float* c) {
    *s = __sinf(x); *c = __cosf(x);
}

// ---------------------------------------------------------------------------
// eA^T precompute, swizzled: g_eAtS[d][64c+8s+i] = eA[64c+8(s^(d&7))+i][d].
// ---------------------------------------------------------------------------
__global__ __launch_bounds__(256) void ker_pre(const float* __restrict__ pts,
                                               const float* __restrict__ A) {
    const int dd = blockIdx.x;           // 0..255
    const int t  = threadIdx.x;          // 64-col chunk c = t
    const float a0 = A[dd], a1 = A[DH + dd], a2 = A[2*DH + dd];
    f16* rowc = &g_eAtS[(size_t)dd*NPTS + t*64];
    f16* rows = &g_eAtS[(size_t)(DH + dd)*NPTS + t*64];
    const int sx = dd & 7;
    #pragma unroll
    for (int s = 0; s < 8; ++s) {
        const int nb = t*64 + 8*(s ^ sx);
        f16x8 vc, vs;
        #pragma unroll
        for (int i = 0; i < 8; ++i) {
            const float* pr = pts + (size_t)(nb + i)*3;
            float sn, cs_; fsincos(pr[0]*a0 + pr[1]*a1 + pr[2]*a2, &sn, &cs_);
            vc[i] = (f16)cs_; vs[i] = (f16)sn;
        }
        *(f16x8*)(rowc + 8*s) = vc;
        *(f16x8*)(rows + 8*s) = vs;
    }
}

// ---------------------------------------------------------------------------
// GEMM1: T = eB^T eA. Block: M=128 (64 q x {cos,sin}), N=256 d, BK=64 n.
// Grid (64,2,4) = 1024 blocks. 512 thr, 8 waves (2M x 4N), wave-tile 64x64.
// A (eB) trig -> XOR-swizzled ds_write [128][64] (0 conflicts);
// B (eA^T) swizzled global_load_lds. 2-barrier schedule (session optimum).
// ---------------------------------------------------------------------------
__global__ __launch_bounds__(512) void ker_T(const float* __restrict__ pts,
                                             const float* __restrict__ B) {
    const int q0 = blockIdx.x * 64;
    const int d0 = blockIdx.y * 256;
    const int ks = blockIdx.z;               // n range [ks*4096, +4096)
    const int t  = threadIdx.x;
    const int lane = t & 63, wid = t >> 6;
    const int wm = wid >> 2, wn = wid & 3;
    const int l7 = lane & 7;

    __shared__ f16 Al[128][64];    // rows 0..63 cos q, 64..127 sin q (XOR-swz)
    __shared__ f16 Bl[256][64];    // [d][n] swizzled (gload_lds dest)

    f32x4 acc[4][4];
    #pragma unroll
    for (int a = 0; a < 4; ++a)
        #pragma unroll
        for (int bq = 0; bq < 4; ++bq) acc[a][bq] = (f32x4){0.f,0.f,0.f,0.f};

    // A-trig: qq = t>>3 (0..63), 8 n per iter, logical slot t&7
    const int qq  = t >> 3;
    const int nn0 = (t & 7) * 8;
    const int wsl = ((t & 7) ^ (qq & 7)) * 8;   // physical slot offset (halfs)
    const float b0 = B[q0+qq], b1 = B[PH+q0+qq], b2 = B[2*PH+q0+qq];
    // B gload: wave covers rows 32*wid..+31 in 4 gloads of 8 rows each
    const size_t bsrc0 = (size_t)(d0 + 32*wid + (lane >> 3))*NPTS + 8*l7;
    // frag coords
    const int mrow = wm*64 + (lane & 15);
    const int ncol = wn*64 + (lane & 15);

    for (int c = 0; c < 64; ++c) {
        const int nb = ks*4096 + c*64;
        __syncthreads();   // previous compute's LDS reads done
        // B stage first (HBM latency hides under trig)
        #pragma unroll
        for (int i = 0; i < 4; ++i)
            gload16(&g_eAtS[0] + bsrc0 + (size_t)(8*i)*NPTS + (size_t)nb,
                    &Bl[32*wid + 8*i][0]);
        {   // A stage: 8 consecutive pts rows = 24 contiguous floats
            const float* pb = pts + (size_t)(nb + nn0)*3;
            const float4 F0 = *(const float4*)(pb);
            const float4 F1 = *(const float4*)(pb + 4);
            const float4 F2 = *(const float4*)(pb + 8);
            const float4 F3 = *(const float4*)(pb + 12);
            const float4 F4 = *(const float4*)(pb + 16);
            const float4 F5 = *(const float4*)(pb + 20);
            const float xx[8] = {F0.x, F0.w, F1.z, F2.y, F3.x, F3.w, F4.z, F5.y};
            const float yy[8] = {F0.y, F1.x, F1.w, F2.z, F3.y, F4.x, F4.w, F5.z};
            const float zz[8] = {F0.z, F1.y, F2.x, F2.w, F3.z, F4.y, F5.x, F5.w};
            f16x8 vc, vs;
            #pragma unroll
            for (int u = 0; u < 8; ++u) {
                float sn, cc; fsincos(xx[u]*b0 + yy[u]*b1 + zz[u]*b2, &sn, &cc);
                vc[u] = (f16)cc; vs[u] = (f16)sn;
            }
            *(f16x8*)&Al[qq][wsl]      = vc;   // (64+qq)&7 == qq&7
            *(f16x8*)&Al[64 + qq][wsl] = vs;
        }
        __syncthreads();   // drains vmcnt+lgkmcnt (compiler-emitted)
        #pragma unroll
        for (int kk = 0; kk < 2; ++kk) {
            f16x8 af[4], bf[4];
            #pragma unroll
            for (int mf = 0; mf < 4; ++mf)   // (mrow+mf*16)&7 == l7
                af[mf] = *(const f16x8*)&Al[mrow + mf*16][(((lane >> 4) + 4*kk) ^ l7)*8];
            #pragma unroll
            for (int nf = 0; nf < 4; ++nf)
                bf[nf] = *(const f16x8*)&Bl[ncol + nf*16][(((lane >> 4) + 4*kk) ^ l7)*8];
            #pragma unroll
            for (int mf = 0; mf < 4; ++mf)
                #pragma unroll
                for (int nf = 0; nf < 4; ++nf)
                    acc[mf][nf] = __builtin_amdgcn_mfma_f32_16x16x32_f16(
                        af[mf], bf[nf], acc[mf][nf], 0, 0, 0);
        }
    }
    // epilogue: wave wm: 0=cos rows, 1=sin rows; D row=(l>>4)*4+j, col=l&15
    #pragma unroll
    for (int mf = 0; mf < 4; ++mf) {
        const int qrow = q0 + mf*16 + (lane >> 4)*4;
        #pragma unroll
        for (int nf = 0; nf < 4; ++nf) {
            const int d = d0 + wn*64 + nf*16 + (lane & 15);
            f16x4 v;
            #pragma unroll
            for (int j = 0; j < 4; ++j) v[j] = (f16)acc[mf][nf][j];
            *(f16x4*)&g_Tt[ks][d][(size_t)wm*PH + qrow] = v;
        }
    }
}

// ---------------------------------------------------------------------------
// Sum 4 T partials -> g_TsS: interleaved [d][2q+cs], XOR-8 swizzled per
// 64-half chunk (physical slot s holds logical slot s^(d&7)).
// ---------------------------------------------------------------------------
__global__ __launch_bounds__(256) void ker_tsum() {
    const int u  = blockIdx.x*256 + threadIdx.x;   // 2048 blocks x 256 thr
    const int d  = u >> 10;                        // 0..511
    const int jj = u & 1023;
    const int c = jj >> 3, s = jj & 7;
    const int klb = 64*c + 8*(s ^ (d & 7));        // logical interleaved-k base
    const int q0_ = klb >> 1;                      // 4 q values
    float oc[4] = {0,0,0,0}, os[4] = {0,0,0,0};
    #pragma unroll
    for (int z = 0; z < 4; ++z) {
        const f16x4 a  = *(const f16x4*)&g_Tt[z][d][q0_];
        const f16x4 bs = *(const f16x4*)&g_Tt[z][d][PH + q0_];
        #pragma unroll
        for (int j = 0; j < 4; ++j) { oc[j] += (float)a[j]; os[j] += (float)bs[j]; }
    }
    f16x8 v;
    #pragma unroll
    for (int j = 0; j < 4; ++j) { v[2*j] = (f16)oc[j]; v[2*j+1] = (f16)os[j]; }
    *(f16x8*)&g_TsS[(size_t)d*(2*PH) + 64*c + 8*s] = v;
}

// ---------------------------------------------------------------------------
// GEMM2: G = eB T. Block: M=128 n, N=256 d, BK=64 interleaved k (=32 q x cs).
// Grid (128,2,2) = 512 blocks. 512 thr, 8 waves (2M x 4N), wave-tile 64x64.
// A (eB cos/sin interleaved) trig -> XOR-swizzled ds_write [128][64];
// B (g_TsS) swizzled global_load_lds.
// ---------------------------------------------------------------------------
__global__ __launch_bounds__(512) void ker_G(const float* __restrict__ pts,
                                             const float* __restrict__ B) {
    const int n0 = blockIdx.x * 128;
    const int d0 = blockIdx.y * 256;
    const int ks = blockIdx.z;               // ik range [ks*4096, +4096)
    const int t  = threadIdx.x;
    const int lane = t & 63, wid = t >> 6;
    const int wm = wid >> 2, wn = wid & 3;
    const int l7 = lane & 7;

    __shared__ f16 Al[128][64];    // [n][ik] XOR-swizzled
    __shared__ f16 Bl[256][64];    // [d][ik] swizzled (gload_lds dest)

    f32x4 acc[4][4];
    #pragma unroll
    for (int a = 0; a < 4; ++a)
        #pragma unroll
        for (int bq = 0; bq < 4; ++bq) acc[a][bq] = (f32x4){0.f,0.f,0.f,0.f};

    // A-trig: nn = t>>2 (0..127); logical slots 2*(t&3), 2*(t&3)+1
    const int nn   = t >> 2;
    const int qch8 = (t & 3) * 8;
    const int sl0  = 2*(t & 3);
    const int sx   = nn & 7;
    const float px = pts[(size_t)(n0+nn)*3];
    const float py = pts[(size_t)(n0+nn)*3 + 1];
    const float pz = pts[(size_t)(n0+nn)*3 + 2];
    // B gload: wave covers d-rows 32*wid..+31 in 4 gloads of 8 rows each
    const size_t bsrc0 = (size_t)(d0 + 32*wid + (lane >> 3))*(2*PH) + 8*l7;
    const int mrow = wm*64 + (lane & 15);
    const int ncol = wn*64 + (lane & 15);

    for (int c = 0; c < 64; ++c) {
        const int ikb = ks*4096 + c*64;      // interleaved-k base
        const int qb  = ikb >> 1;            // q base
        __syncthreads();
        // B stage first (HBM/L3 latency hides under trig)
        #pragma unroll
        for (int i = 0; i < 4; ++i)
            gload16(&g_TsS[0] + bsrc0 + (size_t)(8*i)*(2*PH) + (size_t)ikb,
                    &Bl[32*wid + 8*i][0]);
        {   // A stage: 8 betas -> 16 interleaved (cos,sin) halfs
            const int qg = qb + qch8;
            const float4 X0 = *(const float4*)&B[qg];
            const float4 X1 = *(const float4*)&B[qg + 4];
            const float4 Y0 = *(const float4*)&B[PH + qg];
            const float4 Y1 = *(const float4*)&B[PH + qg + 4];
            const float4 Z0 = *(const float4*)&B[2*PH + qg];
            const float4 Z1 = *(const float4*)&B[2*PH + qg + 4];
            const float bx[8] = {X0.x,X0.y,X0.z,X0.w, X1.x,X1.y,X1.z,X1.w};
            const float by[8] = {Y0.x,Y0.y,Y0.z,Y0.w, Y1.x,Y1.y,Y1.z,Y1.w};
            const float bz[8] = {Z0.x,Z0.y,Z0.z,Z0.w, Z1.x,Z1.y,Z1.z,Z1.w};
            f16x8 v0, v1;
            #pragma unroll
            for (int u = 0; u < 8; ++u) {
                float sn, cc; fsincos(px*bx[u] + py*by[u] + pz*bz[u], &sn, &cc);
                if (u < 4) { v0[2*u]     = (f16)cc; v0[2*u+1]     = (f16)sn; }
                else       { v1[2*(u-4)] = (f16)cc; v1[2*(u-4)+1] = (f16)sn; }
            }
            *(f16x8*)&Al[nn][((sl0    ) ^ sx)*8] = v0;
            *(f16x8*)&Al[nn][((sl0 + 1) ^ sx)*8] = v1;
        }
        __syncthreads();
        #pragma unroll
        for (int kk = 0; kk < 2; ++kk) {
            f16x8 af[4], bf[4];
            #pragma unroll
            for (int mf = 0; mf < 4; ++mf)   // (mrow+mf*16)&7 == l7
                af[mf] = *(const f16x8*)&Al[mrow + mf*16][(((lane >> 4) + 4*kk) ^ l7)*8];
            #pragma unroll
            for (int nf = 0; nf < 4; ++nf)
                bf[nf] = *(const f16x8*)&Bl[ncol + nf*16][(((lane >> 4) + 4*kk) ^ l7)*8];
            #pragma unroll
            for (int mf = 0; mf < 4; ++mf)
                #pragma unroll
                for (int nf = 0; nf < 4; ++nf)
                    acc[mf][nf] = __builtin_amdgcn_mfma_f32_16x16x32_f16(
                        af[mf], bf[nf], acc[mf][nf], 0, 0, 0);
        }
    }
    // epilogue -> g_G[ks][n][d] fp32
    #pragma unroll
    for (int mf = 0; mf < 4; ++mf) {
        const int nbase = n0 + wm*64 + mf*16 + (lane >> 4)*4;
        #pragma unroll
        for (int nf = 0; nf < 4; ++nf) {
            const int d = d0 + wn*64 + nf*16 + (lane & 15);
            #pragma unroll
            for (int j = 0; j < 4; ++j)
                g_G[ks][nbase + j][d] = acc[mf][nf][j];
        }
    }
}

// ---------------------------------------------------------------------------
// Epilogue: Gc = (Gr+i*Gi)*conj(e^{i alpha}) (|e^{ia}|=1, divide==conj-mult;
// rotation preserves row norm -> scale = 16/||G row||). Output = REAL part.
// ---------------------------------------------------------------------------
__global__ __launch_bounds__(256) void ker_fin(const float* __restrict__ pts,
                                               const float* __restrict__ A,
                                               float* __restrict__ out) {
    const int n = blockIdx.x;
    const int k = threadIdx.x;  // 0..255
    const float p0 = pts[(size_t)n*3], p1 = pts[(size_t)n*3+1], p2 = pts[(size_t)n*3+2];
    const float alp = p0*A[k] + p1*A[DH + k] + p2*A[2*DH + k];
    float sa, ca; fsincos(alp, &sa, &ca);
    const float Gr = g_G[0][n][k]      + g_G[1][n][k];
    const float Gi = g_G[0][n][DH + k] + g_G[1][n][DH + k];
    const float Re = Gr*ca + Gi*sa;
    float nr = Gr*Gr + Gi*Gi;
    #pragma unroll
    for (int off = 32; off > 0; off >>= 1) nr += __shfl_down(nr, off, 64);
    __shared__ float wsum[4];
    if ((k & 63) == 0) wsum[k >> 6] = nr;
    __syncthreads();
    const float total = wsum[0] + wsum[1] + wsum[2] + wsum[3];
    const float scale = 16.0f * rsqrtf(total);
    out[(size_t)n*DH + k] = Re * scale;
}

extern "C" void kernel_launch(void* const* d_in, const int* in_sizes, int n_in,
                              void* d_out, int out_size, void* d_ws, size_t ws_size,
                              hipStream_t stream) {
    const float* pts = (const float*)d_in[0];
    const float* A   = (const float*)d_in[1];
    const float* B   = (const float*)d_in[2];
    float* out = (float*)d_out;
    (void)d_ws; (void)ws_size; (void)out_size;

    ker_pre <<<256, 256, 0, stream>>>(pts, A);
    ker_T   <<<dim3(64, 2, 4), 512, 0, stream>>>(pts, B);
    ker_tsum<<<2048, 256, 0, stream>>>();
    ker_G   <<<dim3(128, 2, 2), 512, 0, stream>>>(pts, B);
    ker_fin <<<16384, 256, 0, stream>>>(pts, A, out);
}